// Round 4
// baseline (980.599 us; speedup 1.0000x reference)
//
#include <hip/hip_runtime.h>

typedef unsigned short u16;
typedef short bf16x8 __attribute__((ext_vector_type(8)));
typedef float f32x4 __attribute__((ext_vector_type(4)));

#define BSZ 8192
#define OUTLD 7168

#define BAR_()  __builtin_amdgcn_s_barrier()
#define PIN_()  __builtin_amdgcn_sched_barrier(0)
#define LGKM0_() asm volatile("s_waitcnt lgkmcnt(0)" ::: "memory")
#define VM0_()   asm volatile("s_waitcnt vmcnt(0)" ::: "memory")

__device__ __forceinline__ u16 f2bf(float f) {
  union { float f; unsigned u; } v; v.f = f;
  unsigned r = v.u + 0x7FFFu + ((v.u >> 16) & 1u);
  return (u16)(r >> 16);
}
__device__ __forceinline__ float bf2f(u16 h) {
  union { unsigned u; float f; } v; v.u = ((unsigned)h) << 16;
  return v.f;
}
__device__ __forceinline__ float sigmoidf_(float x) { return 1.0f / (1.0f + __expf(-x)); }

__device__ __forceinline__ void gload16(const u16* g, u16* l) {
  __builtin_amdgcn_global_load_lds(
      (const __attribute__((address_space(1))) void*)g,
      (__attribute__((address_space(3))) void*)l, 16, 0, 0);
}

// ---- is_first dtype detection ----
__global__ void k_detect(const unsigned* __restrict__ isf, int* __restrict__ flag) {
  __shared__ unsigned red;
  if (threadIdx.x == 0) red = 0u;
  __syncthreads();
  unsigned v = 0;
  for (int i = threadIdx.x; i < 2048; i += 256) v |= isf[i];
  atomicOr(&red, v);
  __syncthreads();
  if (threadIdx.x == 0)
    *flag = (((red & 0xFFFFFF00u) != 0u) && ((red & 0xFEFEFEFEu) == 0u)) ? 1 : 0;
}

__device__ __forceinline__ bool is_first_row(const void* isf, int fl, int b) {
  return fl ? (((const unsigned char*)isf)[b] != 0) : (((const int*)isf)[b] != 0);
}

// ---- f32 -> bf16 convert, optional per-row is_first zeroing ----
__global__ void k_reset_cvt(const float* __restrict__ src, u16* __restrict__ dst,
                            const void* __restrict__ isf, const int* __restrict__ flag,
                            int c4, long n4, int doReset) {
  int fl = flag ? *flag : 0;
  long stride = (long)gridDim.x * blockDim.x;
  for (long i = blockIdx.x * (long)blockDim.x + threadIdx.x; i < n4; i += stride) {
    float4 v = ((const float4*)src)[i];
    if (doReset && is_first_row(isf, fl, (int)(i / c4))) { v.x = v.y = v.z = v.w = 0.f; }
    ushort4 o; o.x = f2bf(v.x); o.y = f2bf(v.y); o.z = f2bf(v.z); o.w = f2bf(v.w);
    ((ushort4*)dst)[i] = o;
  }
}

// ---- GRU weight cvt with gate-interleave row permutation ----
// dst row (within blk): rP = (s>>4)*48 + g*16 + (s&15), from src row g*512+s.
__global__ void k_cvt_gruW(const float* __restrict__ src, u16* __restrict__ dst,
                           int ldk, long n8) {
  long stride = (long)gridDim.x * blockDim.x;
  int kc = ldk >> 3;
  for (long i = blockIdx.x * (long)blockDim.x + threadIdx.x; i < n8; i += stride) {
    int j = (int)(i % kc); long row = i / kc;
    long blk = row / 1536; int rP = (int)(row % 1536);
    int sHi = rP / 48, rem = rP % 48, g = rem >> 4, sLo = rem & 15;
    int srow = g * 512 + sHi * 16 + sLo;
    const float* s = src + (blk * 1536 + srow) * (long)ldk + j * 8;
    float4 v0 = ((const float4*)s)[0], v1 = ((const float4*)s)[1];
    ushort4 o0; o0.x = f2bf(v0.x); o0.y = f2bf(v0.y); o0.z = f2bf(v0.z); o0.w = f2bf(v0.w);
    ushort4 o1; o1.x = f2bf(v1.x); o1.y = f2bf(v1.y); o1.z = f2bf(v1.z); o1.w = f2bf(v1.w);
    ((ushort4*)(dst + i * 8))[0] = o0;
    ((ushort4*)(dst + i * 8))[1] = o1;
  }
}

// ---- action normalize + tiny K=8 encoder -> x[:, 0:1024] ----
__global__ void k_ae(const float* __restrict__ act, const float* __restrict__ Wact,
                     const float* __restrict__ bact, u16* __restrict__ x) {
  long stride = (long)gridDim.x * blockDim.x;
  for (long t = blockIdx.x * (long)blockDim.x + threadIdx.x; t < (long)BSZ * 256; t += stride) {
    int b = (int)(t >> 8), h0 = (int)(t & 255) * 4;
    float4 a0 = ((const float4*)act)[b * 2];
    float4 a1 = ((const float4*)act)[b * 2 + 1];
    float mag = fmaxf(
        fmaxf(fmaxf(fabsf(a0.x), fabsf(a0.y)), fmaxf(fabsf(a0.z), fabsf(a0.w))),
        fmaxf(fmaxf(fabsf(a1.x), fabsf(a1.y)), fmaxf(fabsf(a1.z), fabsf(a1.w))));
    float inv = 1.0f / fmaxf(mag, 1.0f);
    ushort4 o;
    u16* op = (u16*)&o;
#pragma unroll
    for (int j = 0; j < 4; ++j) {
      int h = h0 + j;
      float4 w0 = ((const float4*)Wact)[h * 2];
      float4 w1 = ((const float4*)Wact)[h * 2 + 1];
      float dot = a0.x * w0.x + a0.y * w0.y + a0.z * w0.z + a0.w * w0.w
                + a1.x * w1.x + a1.y * w1.y + a1.z * w1.z + a1.w * w1.w;
      op[j] = f2bf(dot * inv + bact[h]);
    }
    *(ushort4*)&x[(long)b * 2048 + h0] = o;
  }
}

// ======== 256x256 8-wave 4-phase/K-tile pipelined GEMM (T2+T3+T4+T5) ========
// NT form: A [M,K] row-major, W [N,K] row-major. C = A1@W1^T (+A2@W2^T) + bias.
// blockIdx.z selects descriptor (fused independent GEMMs).
struct GDesc {
  const u16* A1; const u16* A2;
  int lda1, lda2, K1, K2;
  const u16* W1; const u16* W2;
  int ldw1, ldw2;
  const float* bias;
  float* outF; int ldoF;
  u16* outB; int ldoB;
  int actSilu;
};

__global__ __launch_bounds__(512, 2) void gemm256(GDesc d0, GDesc d1) {
  const GDesc d = blockIdx.z ? d1 : d0;
  __shared__ __align__(16) u16 lsA[2 * 16384];
  __shared__ __align__(16) u16 lsB[2 * 16384];
  const int tid = threadIdx.x;
  const int wave = tid >> 6, lane = tid & 63;
  const int wm = wave >> 2, wn = wave & 3;
  const int lrow = lane & 15, lq = lane >> 4, lr7 = lane & 7;
  const int m0 = blockIdx.y * 256, n0 = blockIdx.x * 256;
  const int swz0 = (lq ^ lr7) * 8, swz1 = ((4 | lq) ^ lr7) * 8;
  const int sRow8 = lane >> 3;
  const int sCol = ((lane & 7) ^ sRow8) * 8;
  const int NT1 = d.K1 >> 6;
  const int NT = NT1 + (d.K2 >> 6);

  auto stageA = [&](int t, int rnd, int buf) {
    const int row = m0 + rnd * 64 + wave * 8 + sRow8;
    const u16* src = (t < NT1)
        ? d.A1 + (long)row * d.lda1 + t * 64 + sCol
        : d.A2 + (long)row * d.lda2 + (t - NT1) * 64 + sCol;
    gload16(src, &lsA[buf * 16384 + rnd * 4096 + wave * 512]);
  };
  auto stageB = [&](int t, int rnd, int buf) {
    const int row = n0 + rnd * 64 + wave * 8 + sRow8;
    const u16* src = (t < NT1)
        ? d.W1 + (long)row * d.ldw1 + t * 64 + sCol
        : d.W2 + (long)row * d.ldw2 + (t - NT1) * 64 + sCol;
    gload16(src, &lsB[buf * 16384 + rnd * 4096 + wave * 512]);
  };

  const f32x4 z4 = {0.f, 0.f, 0.f, 0.f};
  f32x4 acc[8][4];
#pragma unroll
  for (int m = 0; m < 8; ++m)
#pragma unroll
    for (int c = 0; c < 4; ++c) acc[m][c] = z4;

  // prologue: stage tile 0 -> buf0
#pragma unroll
  for (int r = 0; r < 4; ++r) { stageA(0, r, 0); stageB(0, r, 0); }
  VM0_(); BAR_(); PIN_();

  int cur = 0;
#pragma unroll 1
  for (int t = 0; t < NT; ++t) {
    const int nxt = cur ^ 1, tn = t + 1;
    const u16* rA = lsA + cur * 16384 + (wm * 128 + lrow) * 64;
    const u16* rB = lsB + cur * 16384 + (wn * 64 + lrow) * 64;
    bf16x8 bf[4], af[4];
    // ---- P0: quad m0-3 x n0-3, kk0
    if (tn < NT) { stageA(tn, 0, nxt); stageA(tn, 1, nxt); stageB(tn, 0, nxt); }
#pragma unroll
    for (int c = 0; c < 4; ++c) bf[c] = *(const bf16x8*)(rB + c * 1024 + swz0);
#pragma unroll
    for (int m = 0; m < 4; ++m) af[m] = *(const bf16x8*)(rA + m * 1024 + swz0);
    BAR_(); PIN_(); LGKM0_(); PIN_();
    __builtin_amdgcn_s_setprio(1);
#pragma unroll
    for (int m = 0; m < 4; ++m)
#pragma unroll
      for (int c = 0; c < 4; ++c)
        acc[m][c] = __builtin_amdgcn_mfma_f32_16x16x32_bf16(af[m], bf[c], acc[m][c], 0, 0, 0);
    __builtin_amdgcn_s_setprio(0);
    BAR_(); PIN_();
    // ---- P1: quad m4-7 x n0-3, kk0
    if (tn < NT) { stageA(tn, 2, nxt); stageA(tn, 3, nxt); stageB(tn, 1, nxt); }
#pragma unroll
    for (int m = 0; m < 4; ++m) af[m] = *(const bf16x8*)(rA + (4 + m) * 1024 + swz0);
    BAR_(); PIN_(); LGKM0_(); PIN_();
    __builtin_amdgcn_s_setprio(1);
#pragma unroll
    for (int m = 0; m < 4; ++m)
#pragma unroll
      for (int c = 0; c < 4; ++c)
        acc[4 + m][c] = __builtin_amdgcn_mfma_f32_16x16x32_bf16(af[m], bf[c], acc[4 + m][c], 0, 0, 0);
    __builtin_amdgcn_s_setprio(0);
    BAR_(); PIN_();
    // ---- P2: quad m0-3, kk1
    if (tn < NT) { stageB(tn, 2, nxt); stageB(tn, 3, nxt); }
#pragma unroll
    for (int c = 0; c < 4; ++c) bf[c] = *(const bf16x8*)(rB + c * 1024 + swz1);
#pragma unroll
    for (int m = 0; m < 4; ++m) af[m] = *(const bf16x8*)(rA + m * 1024 + swz1);
    BAR_(); PIN_(); LGKM0_(); PIN_();
    __builtin_amdgcn_s_setprio(1);
#pragma unroll
    for (int m = 0; m < 4; ++m)
#pragma unroll
      for (int c = 0; c < 4; ++c)
        acc[m][c] = __builtin_amdgcn_mfma_f32_16x16x32_bf16(af[m], bf[c], acc[m][c], 0, 0, 0);
    __builtin_amdgcn_s_setprio(0);
    BAR_(); PIN_();
    // ---- P3: quad m4-7, kk1 + tile-boundary counted wait
#pragma unroll
    for (int m = 0; m < 4; ++m) af[m] = *(const bf16x8*)(rA + (4 + m) * 1024 + swz1);
    BAR_(); PIN_(); LGKM0_(); PIN_();
    __builtin_amdgcn_s_setprio(1);
#pragma unroll
    for (int m = 0; m < 4; ++m)
#pragma unroll
      for (int c = 0; c < 4; ++c)
        acc[4 + m][c] = __builtin_amdgcn_mfma_f32_16x16x32_bf16(af[m], bf[c], acc[4 + m][c], 0, 0, 0);
    __builtin_amdgcn_s_setprio(0);
    VM0_();   // only next-tile loads outstanding; issued 2-3 phases ago
    BAR_(); PIN_();
    cur = nxt;
  }

  // epilogue
#pragma unroll
  for (int c = 0; c < 4; ++c) {
    const int col = n0 + wn * 64 + c * 16 + lrow;
    const float bv = d.bias ? d.bias[col] : 0.f;
#pragma unroll
    for (int m = 0; m < 8; ++m) {
      const int rowb = m0 + wm * 128 + m * 16 + lq * 4;
#pragma unroll
      for (int r = 0; r < 4; ++r) {
        float v = acc[m][c][r] + bv;
        if (d.actSilu) v = v * sigmoidf_(v);
        if (d.outF) d.outF[(long)(rowb + r) * d.ldoF + col] = v;
        if (d.outB) d.outB[(long)(rowb + r) * d.ldoB + col] = f2bf(v);
      }
    }
  }
}

// ======== block-diagonal GRU, 256-row tile, 8-wave 4-phase pipeline ========
// Weights pre-permuted: row rP = (s>>4)*48 + g*16 + (s&15) -> wave's 3 N-frags
// are gates {r,u,z} for the same 16 s-columns.
__global__ __launch_bounds__(512, 2) void gru256(
    const u16* __restrict__ xbuf, const u16* __restrict__ hbuf,
    const u16* __restrict__ WihP, const u16* __restrict__ WhhP,
    const float* __restrict__ bih, const float* __restrict__ bhh,
    float* __restrict__ outF, u16* __restrict__ hnew)
{
  __shared__ __align__(16) u16 lsA[2 * 16384];
  __shared__ __align__(16) u16 lsW[2 * 12288];
  const int tid = threadIdx.x;
  const int wave = tid >> 6, lane = tid & 63;
  const int wm = wave >> 2, wn = wave & 3;
  const int lrow = lane & 15, lq = lane >> 4, lr7 = lane & 7;
  const int m0 = blockIdx.y * 256;
  const int nt_ = blockIdx.x;          // 0..63
  const int blk = nt_ >> 3, stile = nt_ & 7;
  const int swz0 = (lq ^ lr7) * 8, swz1 = ((4 | lq) ^ lr7) * 8;
  const int sRow8 = lane >> 3;
  const int sCol = ((lane & 7) ^ sRow8) * 8;
  const int NT = 12;  // 4 x-tiles (K=256) + 8 h-tiles (K=512)

  auto stageA = [&](int t, int rnd, int buf) {
    const int row = m0 + rnd * 64 + wave * 8 + sRow8;
    const u16* src = (t < 4)
        ? xbuf + (long)row * 2048 + blk * 256 + t * 64 + sCol
        : hbuf + (long)row * 4096 + blk * 512 + (t - 4) * 64 + sCol;
    gload16(src, &lsA[buf * 16384 + rnd * 4096 + wave * 512]);
  };
  auto stageW = [&](int t, int rnd, int buf) {
    const long row = (long)blk * 1536 + stile * 192 + rnd * 64 + wave * 8 + sRow8;
    const u16* src = (t < 4)
        ? WihP + row * 256 + t * 64 + sCol
        : WhhP + row * 512 + (t - 4) * 64 + sCol;
    gload16(src, &lsW[buf * 12288 + rnd * 4096 + wave * 512]);
  };

  const f32x4 z4 = {0.f, 0.f, 0.f, 0.f};
  f32x4 acc[8][3];
#pragma unroll
  for (int m = 0; m < 8; ++m)
#pragma unroll
    for (int g = 0; g < 3; ++g) acc[m][g] = z4;

  // prologue
#pragma unroll
  for (int r = 0; r < 4; ++r) stageA(0, r, 0);
#pragma unroll
  for (int r = 0; r < 3; ++r) stageW(0, r, 0);
  VM0_(); BAR_(); PIN_();

  int cur = 0;
#pragma unroll 1
  for (int t = 0; t < NT; ++t) {
    const int nxt = cur ^ 1, tn = t + 1;
    const u16* rA = lsA + cur * 16384 + (wm * 128 + lrow) * 64;
    const u16* rW = lsW + cur * 12288 + (wn * 48 + lrow) * 64;
    bf16x8 wf[3], af[4];
    // ---- P0: m0-3 x g0-2, kk0
    if (tn < NT) { stageA(tn, 0, nxt); stageA(tn, 1, nxt); stageW(tn, 0, nxt); }
#pragma unroll
    for (int g = 0; g < 3; ++g) wf[g] = *(const bf16x8*)(rW + g * 1024 + swz0);
#pragma unroll
    for (int m = 0; m < 4; ++m) af[m] = *(const bf16x8*)(rA + m * 1024 + swz0);
    BAR_(); PIN_(); LGKM0_(); PIN_();
    __builtin_amdgcn_s_setprio(1);
#pragma unroll
    for (int m = 0; m < 4; ++m)
#pragma unroll
      for (int g = 0; g < 3; ++g)
        acc[m][g] = __builtin_amdgcn_mfma_f32_16x16x32_bf16(af[m], wf[g], acc[m][g], 0, 0, 0);
    __builtin_amdgcn_s_setprio(0);
    BAR_(); PIN_();
    // ---- P1: m4-7, kk0
    if (tn < NT) { stageA(tn, 2, nxt); stageA(tn, 3, nxt); stageW(tn, 1, nxt); }
#pragma unroll
    for (int m = 0; m < 4; ++m) af[m] = *(const bf16x8*)(rA + (4 + m) * 1024 + swz0);
    BAR_(); PIN_(); LGKM0_(); PIN_();
    __builtin_amdgcn_s_setprio(1);
#pragma unroll
    for (int m = 0; m < 4; ++m)
#pragma unroll
      for (int g = 0; g < 3; ++g)
        acc[4 + m][g] = __builtin_amdgcn_mfma_f32_16x16x32_bf16(af[m], wf[g], acc[4 + m][g], 0, 0, 0);
    __builtin_amdgcn_s_setprio(0);
    BAR_(); PIN_();
    // ---- P2: m0-3, kk1
    if (tn < NT) { stageW(tn, 2, nxt); }
#pragma unroll
    for (int g = 0; g < 3; ++g) wf[g] = *(const bf16x8*)(rW + g * 1024 + swz1);
#pragma unroll
    for (int m = 0; m < 4; ++m) af[m] = *(const bf16x8*)(rA + m * 1024 + swz1);
    BAR_(); PIN_(); LGKM0_(); PIN_();
    __builtin_amdgcn_s_setprio(1);
#pragma unroll
    for (int m = 0; m < 4; ++m)
#pragma unroll
      for (int g = 0; g < 3; ++g)
        acc[m][g] = __builtin_amdgcn_mfma_f32_16x16x32_bf16(af[m], wf[g], acc[m][g], 0, 0, 0);
    __builtin_amdgcn_s_setprio(0);
    BAR_(); PIN_();
    // ---- P3: m4-7, kk1 + boundary wait
#pragma unroll
    for (int m = 0; m < 4; ++m) af[m] = *(const bf16x8*)(rA + (4 + m) * 1024 + swz1);
    BAR_(); PIN_(); LGKM0_(); PIN_();
    __builtin_amdgcn_s_setprio(1);
#pragma unroll
    for (int m = 0; m < 4; ++m)
#pragma unroll
      for (int g = 0; g < 3; ++g)
        acc[4 + m][g] = __builtin_amdgcn_mfma_f32_16x16x32_bf16(af[m], wf[g], acc[4 + m][g], 0, 0, 0);
    __builtin_amdgcn_s_setprio(0);
    VM0_();
    BAR_(); PIN_();
    cur = nxt;
  }

  // fused GRU epilogue
  const int s = stile * 64 + wn * 16 + lrow;
  const int col = blk * 512 + s;
  const long bb = (long)blk * 1536 + s;
  const float br = bih[bb] + bhh[bb];
  const float bu = bih[bb + 512] + bhh[bb + 512];
  const float bc = bih[bb + 1024] + bhh[bb + 1024];
#pragma unroll
  for (int m = 0; m < 8; ++m) {
    const int rowb = m0 + wm * 128 + m * 16 + lq * 4;
#pragma unroll
    for (int r = 0; r < 4; ++r) {
      const int row = rowb + r;
      const float gr = acc[m][0][r] + br;
      const float gu = acc[m][1][r] + bu;
      const float gc = acc[m][2][r] + bc;
      const float rr = sigmoidf_(gr);
      const float uu = sigmoidf_(gu);
      const float cand = tanhf(rr * gc);
      const float h = bf2f(hbuf[(long)row * 4096 + col]);
      const float hn = (1.f - uu) * h + uu * cand;
      outF[(long)row * OUTLD + col] = hn;
      hnew[(long)row * 4096 + col] = f2bf(hn);
    }
  }
}

// ---- softmax over C=32 groups + unimix ----
__global__ void k_softmax(float* __restrict__ out) {
  int t = blockIdx.x * blockDim.x + threadIdx.x;
  if (t >= BSZ * 32) return;
  int b = t >> 5, g = t & 31;
  const float* src = out + (long)b * OUTLD + 4096 + g * 32;
  float* dst = out + (long)b * OUTLD + 5120 + g * 32;
  float v[32];
#pragma unroll
  for (int i = 0; i < 8; ++i) {
    float4 q = ((const float4*)src)[i];
    v[4 * i] = q.x; v[4 * i + 1] = q.y; v[4 * i + 2] = q.z; v[4 * i + 3] = q.w;
  }
  float m = v[0];
#pragma unroll
  for (int i = 1; i < 32; ++i) m = fmaxf(m, v[i]);
  float ssum = 0.f;
#pragma unroll
  for (int i = 0; i < 32; ++i) { v[i] = __expf(v[i] - m); ssum += v[i]; }
  float inv = 0.99f / ssum;
#pragma unroll
  for (int i = 0; i < 8; ++i) {
    float4 q;
    q.x = v[4 * i] * inv + 3.125e-4f;
    q.y = v[4 * i + 1] * inv + 3.125e-4f;
    q.z = v[4 * i + 2] * inv + 3.125e-4f;
    q.w = v[4 * i + 3] * inv + 3.125e-4f;
    ((float4*)dst)[i] = q;
  }
}

extern "C" void kernel_launch(void* const* d_in, const int* in_sizes, int n_in,
                              void* d_out, int out_size, void* d_ws, size_t ws_size,
                              hipStream_t stream) {
  const float* det   = (const float*)d_in[0];
  const float* stoch = (const float*)d_in[1];
  const float* pact  = (const float*)d_in[2];
  const float* embed = (const float*)d_in[3];
  const void*  isf   = d_in[4];
  const float* Wact  = (const float*)d_in[5];
  const float* bact  = (const float*)d_in[6];
  const float* Wst   = (const float*)d_in[7];
  const float* bst   = (const float*)d_in[8];
  const float* Wih   = (const float*)d_in[9];
  const float* bih   = (const float*)d_in[10];
  const float* Whh   = (const float*)d_in[11];
  const float* bhh   = (const float*)d_in[12];
  const float* Wpr1  = (const float*)d_in[13];
  const float* bpr1  = (const float*)d_in[14];
  const float* Wpr2  = (const float*)d_in[15];
  const float* bpr2  = (const float*)d_in[16];
  const float* Wpo1  = (const float*)d_in[17];
  const float* bpo1  = (const float*)d_in[18];
  const float* Wpo2  = (const float*)d_in[19];
  const float* bpo2  = (const float*)d_in[20];
  float* out = (float*)d_out;

  int* flag = (int*)d_ws;
  u16* wsu  = (u16*)((char*)d_ws + 256);
  u16* bWst  = wsu;                   // 1,048,576
  u16* bWihP = wsu + 1048576UL;       // 3,145,728 (permuted)
  u16* bWhhP = wsu + 4194304UL;       // 6,291,456 (permuted)
  u16* bWpr1 = wsu + 10485760UL;      // 4,194,304
  u16* bWpr2 = wsu + 14680064UL;      // 1,048,576
  u16* bWpo1 = wsu + 15728640UL;      // 5,242,880
  u16* bWpo2 = wsu + 20971520UL;      // 1,048,576
  u16* bufX  = wsu + 22020096UL;      // 16,777,216  [B,2048]
  u16* bufSt = wsu + 38797312UL;      // 8,388,608   stoch -> later ph
  u16* bufHb = wsu + 47185920UL;      // 33,554,432  hb -> later qh
  u16* bufHn = wsu + 80740352UL;      // 33,554,432  h_new bf16
  u16* bufEm = wsu + 114294784UL;     // 8,388,608   embed bf16

  k_detect<<<dim3(1), dim3(256), 0, stream>>>((const unsigned*)isf, flag);

  // plain weight conversions
  struct CV { const float* s; u16* d; long n; };
  CV cvs[5] = {
    {Wst, bWst, 1048576L}, {Wpr1, bWpr1, 4194304L}, {Wpr2, bWpr2, 1048576L},
    {Wpo1, bWpo1, 5242880L}, {Wpo2, bWpo2, 1048576L}
  };
  for (int i = 0; i < 5; ++i) {
    long n4 = cvs[i].n / 4;
    int blocks = (int)((n4 + 255) / 256); if (blocks > 4096) blocks = 4096;
    k_reset_cvt<<<dim3(blocks), dim3(256), 0, stream>>>(
        cvs[i].s, cvs[i].d, (const void*)nullptr, (const int*)nullptr, 1, n4, 0);
  }
  // permuted GRU weights
  k_cvt_gruW<<<dim3(1536), dim3(256), 0, stream>>>(Wih, bWihP, 256, 393216L);
  k_cvt_gruW<<<dim3(3072), dim3(256), 0, stream>>>(Whh, bWhhP, 512, 786432L);

  // input prep
  k_ae<<<dim3(2048), dim3(256), 0, stream>>>(pact, Wact, bact, bufX);
  k_reset_cvt<<<dim3(4096), dim3(256), 0, stream>>>(stoch, bufSt, isf, flag, 256, 2097152L, 1);
  k_reset_cvt<<<dim3(4096), dim3(256), 0, stream>>>(det, bufHb, isf, flag, 1024, 8388608L, 1);
  k_reset_cvt<<<dim3(4096), dim3(256), 0, stream>>>(embed, bufEm, (const void*)nullptr,
                                                    (const int*)nullptr, 256, 2097152L, 0);

  GDesc dSe;
  dSe.A1 = bufSt; dSe.A2 = nullptr; dSe.lda1 = 1024; dSe.lda2 = 0;
  dSe.K1 = 1024; dSe.K2 = 0;
  dSe.W1 = bWst; dSe.W2 = nullptr; dSe.ldw1 = 1024; dSe.ldw2 = 0;
  dSe.bias = bst; dSe.outF = nullptr; dSe.ldoF = 0;
  dSe.outB = bufX + 1024; dSe.ldoB = 2048; dSe.actSilu = 0;
  gemm256<<<dim3(4, 32, 1), dim3(512), 0, stream>>>(dSe, dSe);

  gru256<<<dim3(64, 32), dim3(512), 0, stream>>>(bufX, bufHb, bWihP, bWhhP,
                                                 bih, bhh, out, bufHn);

  GDesc dPr1, dPo1;
  dPr1.A1 = bufHn; dPr1.A2 = nullptr; dPr1.lda1 = 4096; dPr1.lda2 = 0;
  dPr1.K1 = 4096; dPr1.K2 = 0;
  dPr1.W1 = bWpr1; dPr1.W2 = nullptr; dPr1.ldw1 = 4096; dPr1.ldw2 = 0;
  dPr1.bias = bpr1; dPr1.outF = nullptr; dPr1.ldoF = 0;
  dPr1.outB = bufSt; dPr1.ldoB = 1024; dPr1.actSilu = 1;
  dPo1.A1 = bufHn; dPo1.A2 = bufEm; dPo1.lda1 = 4096; dPo1.lda2 = 1024;
  dPo1.K1 = 4096; dPo1.K2 = 1024;
  dPo1.W1 = bWpo1; dPo1.W2 = bWpo1 + 4096; dPo1.ldw1 = 5120; dPo1.ldw2 = 5120;
  dPo1.bias = bpo1; dPo1.outF = nullptr; dPo1.ldoF = 0;
  dPo1.outB = bufHb; dPo1.ldoB = 1024; dPo1.actSilu = 1;
  gemm256<<<dim3(4, 32, 2), dim3(512), 0, stream>>>(dPr1, dPo1);

  GDesc dPr2, dPo2;
  dPr2.A1 = bufSt; dPr2.A2 = nullptr; dPr2.lda1 = 1024; dPr2.lda2 = 0;
  dPr2.K1 = 1024; dPr2.K2 = 0;
  dPr2.W1 = bWpr2; dPr2.W2 = nullptr; dPr2.ldw1 = 1024; dPr2.ldw2 = 0;
  dPr2.bias = bpr2; dPr2.outF = out + 4096; dPr2.ldoF = OUTLD;
  dPr2.outB = nullptr; dPr2.ldoB = 0; dPr2.actSilu = 0;
  dPo2.A1 = bufHb; dPo2.A2 = nullptr; dPo2.lda1 = 1024; dPo2.lda2 = 0;
  dPo2.K1 = 1024; dPo2.K2 = 0;
  dPo2.W1 = bWpo2; dPo2.W2 = nullptr; dPo2.ldw1 = 1024; dPo2.ldw2 = 0;
  dPo2.bias = bpo2; dPo2.outF = out + 6144; dPo2.ldoF = OUTLD;
  dPo2.outB = nullptr; dPo2.ldoB = 0; dPo2.actSilu = 0;
  gemm256<<<dim3(4, 32, 2), dim3(512), 0, stream>>>(dPr2, dPo2);

  k_softmax<<<dim3(1024), dim3(256), 0, stream>>>(out);
}